// Round 2
// baseline (419.247 us; speedup 1.0000x reference)
//
#include <hip/hip_runtime.h>
#include <math.h>

// Problem constants
#define HW 65536          // 256*256
#define NPAD 258          // padded spatial dim

typedef short bf16x8 __attribute__((ext_vector_type(8)));
typedef float f32x4  __attribute__((ext_vector_type(4)));

// Workspace layout (bytes)
#define O_COUNTS 0            // 12 * 32 ints = 1536 B
#define O_W2C    2048         // 8 * 16 floats = 512 B
#define O_WT     4096         // 2 convs * 36864 bf16 = 147456 B  [cv][h][tap][q][co][8ci]
#define O_META   151552       // 12 * 65536 ints = 3 MiB
#define O_FUSED  3297280      // 8*258*258*64 bf16 = 68,161,536 B
#define O_X1     71458816     // same size

// Conv LDS: per phase a HALF-CHANNEL tile: 6 rows x 66 px x 64 B (32 ci).
// Row stride 4240 B (4224 + 16 pad). Two buffers (double-buffered phases).
#define HROWB   4224              // 66 px * 64 B
#define HROWSTR 4240
#define HBUFB   (6 * HROWSTR)     // 25440 B per buffer

__device__ __forceinline__ unsigned short f2bf(float f) {
    unsigned int u = __float_as_uint(f);
    u += 0x7FFFu + ((u >> 16) & 1u);   // round-to-nearest-even
    return (unsigned short)(u >> 16);
}

// Fast erf-based GELU (Abramowitz-Stegun 7.1.26, |err_erf| <= 1.5e-7).
// ~15 VALU ops vs ~50 for libm erff. Error is far below bf16 storage noise.
__device__ __forceinline__ float gelu_fast(float v) {
    float x  = v * 0.70710678118654752f;
    float ax = fabsf(x);
    float t  = __builtin_amdgcn_rcpf(fmaf(0.3275911f, ax, 1.0f));
    float p  = fmaf(t, 1.061405429f, -1.453152027f);
    p = fmaf(t, p, 1.421413741f);
    p = fmaf(t, p, -0.284496736f);
    p = fmaf(t, p, 0.254829592f);
    p = p * t;
    float e   = __expf(-x * x);
    float era = fmaf(-p, e, 1.0f);
    float er  = copysignf(era, x);
    return 0.5f * v * (1.0f + er);
}

// ---------------------------------------------------------------------------
// Prep: invert extrinsics, build bf16 weight fragment image [h][tap][q][co][8ci],
// zero padded-buffer borders, zero counts
// ---------------------------------------------------------------------------
__global__ __launch_bounds__(256) void prep_kernel(
    const float* __restrict__ extr, const float* __restrict__ w1,
    const float* __restrict__ w2, float* __restrict__ w2c,
    unsigned short* __restrict__ wT, unsigned short* __restrict__ fusedP,
    unsigned short* __restrict__ x1P, int* __restrict__ counts)
{
    int tid = blockIdx.x * blockDim.x + threadIdx.x;
    int nth = gridDim.x * blockDim.x;

    if (blockIdx.x == 0) {
        if (threadIdx.x < 8) {
            float a[4][8];
            const float* E = extr + threadIdx.x * 16;
            for (int r = 0; r < 4; r++)
                for (int c = 0; c < 4; c++) {
                    a[r][c] = E[r*4 + c];
                    a[r][4+c] = (r == c) ? 1.0f : 0.0f;
                }
            for (int col = 0; col < 4; col++) {
                int piv = col; float bm = fabsf(a[col][col]);
                for (int r = col+1; r < 4; r++) {
                    float v = fabsf(a[r][col]);
                    if (v > bm) { bm = v; piv = r; }
                }
                if (piv != col)
                    for (int c = 0; c < 8; c++) { float t = a[col][c]; a[col][c] = a[piv][c]; a[piv][c] = t; }
                float f = 1.0f / a[col][col];
                for (int c = 0; c < 8; c++) a[col][c] *= f;
                for (int r = 0; r < 4; r++) if (r != col) {
                    float f2 = a[r][col];
                    for (int c = 0; c < 8; c++) a[r][c] -= f2 * a[col][c];
                }
            }
            float* O = w2c + threadIdx.x * 16;
            for (int r = 0; r < 4; r++)
                for (int c = 0; c < 4; c++) O[r*4+c] = a[r][4+c];
        }
    }

    // Zero padded count slots (12 * 32 ints)
    for (int i = tid; i < 384; i += nth) counts[i] = 0;

    // Weight fragment image: 2 convs * [h2][tap9][q4][co64][j8]
    for (int e = tid; e < 73728; e += nth) {
        int t = e;
        int j  = t & 7;  t >>= 3;
        int co = t & 63; t >>= 6;
        int q  = t & 3;  t >>= 2;
        int tap = t % 9; t /= 9;
        int h  = t & 1;  int cv = t >> 1;
        int ci = h*32 + q*8 + j;
        int ky = tap / 3, kx = tap % 3;
        const float* wsrc = cv ? w2 : w1;
        float v = wsrc[((co*64 + ci)*3 + ky)*3 + kx];
        wT[cv*36864 + ((((h*9 + tap)*4 + q)*64 + co)*8 + j)] = f2bf(v);
    }

    // Zero borders of both padded buffers
    for (int u = tid; u < 2*8*1028*8; u += nth) {
        int t = u;
        int ch   = t & 7;    t >>= 3;
        int cell = t % 1028; t /= 1028;
        int n    = t & 7;    int buf = t >> 3;
        int y, x;
        if      (cell < 258) { y = 0;   x = cell; }
        else if (cell < 516) { y = 257; x = cell - 258; }
        else if (cell < 772) { y = cell - 516 + 1; x = 0; }
        else                 { y = cell - 772 + 1; x = 257; }
        unsigned short* p = (buf ? x1P : fusedP) +
            (((size_t)(n*NPAD + y)*NPAD + x)*64 + ch*8);
        *reinterpret_cast<uint4*>(p) = make_uint4(0u, 0u, 0u, 0u);
    }
}

// ---------------------------------------------------------------------------
// Projection: per (b, j->k) pair, compute mask|idx per point + valid counts.
// ---------------------------------------------------------------------------
__global__ __launch_bounds__(256) void proj_kernel(
    const float* __restrict__ means, const float* __restrict__ intr,
    const float* __restrict__ w2c, int* __restrict__ meta,
    int* __restrict__ counts)
{
    const int jt[6] = {0,1,1,2,2,3};
    const int kt[6] = {1,0,2,1,3,2};
    int s = blockIdx.y;            // 0..11
    int b = s / 6, p = s % 6;
    int j = jt[p], k = kt[p];
    int i = blockIdx.x * 256 + threadIdx.x;

    __shared__ int bcnt;
    if (threadIdx.x == 0) bcnt = 0;
    __syncthreads();

    const float* mp = means + ((size_t)(b*4 + j)*HW + i)*3;
    float x = mp[0], y = mp[1], z = mp[2];
    const float* M = w2c + (b*4 + k)*16;
    const float* I = intr + (b*4 + k)*9;

    float cx = fmaf(M[2],  z, fmaf(M[1], y, M[0]*x)) + M[3];
    float cy = fmaf(M[6],  z, fmaf(M[5], y, M[4]*x)) + M[7];
    float cz = fmaf(M[10], z, fmaf(M[9], y, M[8]*x)) + M[11];

    bool vz = cz > 1e-8f;
    float zi = cz + 1e-8f;
    float sx = cx / zi, sy = cy / zi, sz = cz / zi;
    float nx = fmaf(I[2], sz, fmaf(I[1], sy, I[0]*sx));
    float ny = fmaf(I[5], sz, fmaf(I[4], sy, I[3]*sx));

    int px = (int)floorf(nx * 256.0f);
    int py = (int)floorf(ny * 256.0f);
    bool mask = (nx >= 0.0f) && (nx < 1.0f) && (ny >= 0.0f) && (ny < 1.0f) && vz;
    int pxc = min(max(px, 0), 255);
    int pyc = min(max(py, 0), 255);
    int idx = pyc*256 + pxc;
    meta[(size_t)s*HW + i] = idx | (mask ? (int)0x80000000 : 0);

    unsigned long long bal = __ballot(mask ? 1 : 0);
    if ((threadIdx.x & 63) == 0)
        atomicAdd(&bcnt, (int)__popcll(bal));
    __syncthreads();
    if (threadIdx.x == 0)
        atomicAdd(counts + s*32, bcnt);
}

// ---------------------------------------------------------------------------
// Fusion: acc = feats_j + sum_k scale_k * masked_gather(feats_k); /norm; bf16
// ---------------------------------------------------------------------------
__global__ __launch_bounds__(256) void fuse_kernel(
    const float* __restrict__ feats, const int* __restrict__ meta,
    const int* __restrict__ counts, unsigned short* __restrict__ fusedP)
{
    const int nsl[4]    = {1, 2, 2, 1};
    const int slt[4][2] = {{0,0},{1,2},{3,4},{5,5}};
    const int kvw[4][2] = {{1,1},{0,2},{1,3},{2,2}};

    int bj = blockIdx.y;           // n = b*4 + j
    int b = bj >> 2, j = bj & 3;
    int pt = blockIdx.x * 16 + (threadIdx.x >> 4);
    int cg = threadIdx.x & 15;

    const float4* fj = reinterpret_cast<const float4*>(
        feats + ((size_t)bj*HW + pt)*64) + cg;
    float4 acc = *fj;
    float norm = 1.0f;
    int ns = nsl[j];
    for (int e = 0; e < 2; e++) {
        if (e < ns) {
            int p = slt[j][e], k = kvw[j][e];
            int s = b*6 + p;
            float scale = 0.1f * (float)counts[s*32] / 65536.0f;
            int mt = meta[(size_t)s*HW + pt];
            if (mt < 0) {
                int idx = mt & 0xFFFF;
                const float4* g = reinterpret_cast<const float4*>(
                    feats + ((size_t)(b*4 + k)*HW + idx)*64) + cg;
                float4 gv = *g;
                acc.x += scale * gv.x; acc.y += scale * gv.y;
                acc.z += scale * gv.z; acc.w += scale * gv.w;
            }
            norm += scale;
        }
    }
    float ox = acc.x / norm, oy = acc.y / norm;
    float oz = acc.z / norm, ow = acc.w / norm;

    int yy = pt >> 8, xx = pt & 255;
    unsigned short* op = fusedP +
        (((size_t)bj*NPAD + (yy+1))*NPAD + (xx+1))*64 + cg*4;
    ushort4 o = make_ushort4(f2bf(ox), f2bf(oy), f2bf(oz), f2bf(ow));
    *reinterpret_cast<ushort4*>(op) = o;
}

// ---------------------------------------------------------------------------
// 3x3 conv, pipelined: block = 256 thr (4 waves), processes NT=2 y-tiles of
// 4 output rows x 64 px x 64 co. Each tile is split into 2 half-channel
// phases (32 ci each, 25.4 KB LDS), double-buffered: each phase ISSUES the
// next phase's global_load_lds before its 144-MFMA compute, so the barrier's
// vmcnt(0) drain finds the loads already landed (T3 minimum-2-phase).
//
// Half-tile swizzle: 64 B/px = 4 chunks of 16 B; LDS slot (px,c) holds global
// chunk c ^ ((px>>1)&3). A ds_read_b128 by 64 lanes (px = P0+m, chunk q) then
// hits all 8 bank-groups exactly twice (2-way = free) for any P0. Staging
// keeps the LDS dest linear (global_load_lds requirement) and pre-swizzles
// the per-lane GLOBAL source address (involution, both-sides rule).
// MFMA operands swapped (weights=A, pixels=B): lane's D holds 4 contiguous
// co per px -> vectorized 8B/16B stores.
// ---------------------------------------------------------------------------
template<int MODE>
__global__ __launch_bounds__(256) void conv_kernel(
    const unsigned short* __restrict__ in, const unsigned short* __restrict__ wT,
    const float* __restrict__ bias, void* __restrict__ outp)
{
    __shared__ unsigned short smem[2 * HBUFB / 2];   // 50880 B

    int n = blockIdx.z;
    int Y0 = blockIdx.y * 8;       // 8 output rows per block (2 tiles of 4)
    int X0 = blockIdx.x * 64;      // first output px
    int w  = threadIdx.x >> 6;     // wave id: output row (tile-local) w
    int lane = threadIdx.x & 63;
    int m = lane & 15, q = lane >> 4;

    // Staging per-lane source offsets (relative to a (row, h) strip base).
    // Main 4 KB: load i, lane l covers LDS chunk d=i*64+l -> px=d>>2, c=d&3;
    // source chunk = c ^ s(px), s(px)=(px>>1)&3 -> lane part collapses to:
    int srcl = ((lane >> 2) * 128) + ((((lane & 3) ^ ((lane >> 3) & 3)) & 3) << 4);
    // Tail (px 64,65 = 8 chunks, lanes 0..7, s(px)=0 there):
    int tsrcl = 8192 + ((lane >> 2) * 128) + ((lane & 3) << 4);

    // ds_read per-lane bases (one per dx; q fixed per lane so XOR collapses)
    int vb[3];
#pragma unroll
    for (int dx = 0; dx < 3; dx++)
        vb[dx] = w*HROWSTR + m*64 + (((q ^ (((m + dx) >> 1) & 3)) & 3) << 4);

    const char* gin = (const char*)in;

    // Stage half-tile (tile t, channel-half h) into buffer buf.
    auto STAGE = [&](int t, int h, int buf) {
        const char* gb = gin + (((size_t)(n*NPAD) + (size_t)(Y0 + 4*t)) * NPAD + X0) * 128 + h*64;
        char* lb = (char*)smem + buf*HBUFB;
        for (int ri = w; ri < 6; ri += 4) {
            const char* g = gb + (size_t)ri * (NPAD*128);
            char* l = lb + ri*HROWSTR;
#pragma unroll
            for (int i = 0; i < 4; i++)
                __builtin_amdgcn_global_load_lds(
                    (const __attribute__((address_space(1))) unsigned int*)(g + i*2048 + srcl),
                    (__attribute__((address_space(3))) unsigned int*)(l + i*1024 + (size_t)lane*16),
                    16, 0, 0);
            if (lane < 8)
                __builtin_amdgcn_global_load_lds(
                    (const __attribute__((address_space(1))) unsigned int*)(g + tsrcl),
                    (__attribute__((address_space(3))) unsigned int*)(l + 4096 + (size_t)lane*16),
                    16, 0, 0);
        }
    };

    f32x4 acc[4][4];
    auto ACCZERO = [&]() {
#pragma unroll
        for (int a = 0; a < 4; a++)
#pragma unroll
            for (int bq = 0; bq < 4; bq++)
                acc[a][bq] = (f32x4){0.f, 0.f, 0.f, 0.f};
    };

    // 9 taps of the half-channel (K=32 per tap -> 1 MFMA per (Mt,Nt))
    auto COMPUTE = [&](int h, int buf) {
        const char* sb = (const char*)smem + buf*HBUFB;
        const char* wb = (const char*)wT + h*9*4096 + q*1024 + m*16;
#pragma unroll
        for (int tap = 0; tap < 9; tap++) {
            int dy = tap/3, dx = tap%3;
            bf16x8 av[4], bv[4];
#pragma unroll
            for (int Mt = 0; Mt < 4; Mt++)
                av[Mt] = *reinterpret_cast<const bf16x8*>(
                    sb + vb[dx] + dy*HROWSTR + Mt*1024 + dx*64);
#pragma unroll
            for (int Nt = 0; Nt < 4; Nt++)
                bv[Nt] = *reinterpret_cast<const bf16x8*>(wb + tap*4096 + Nt*256);
#pragma unroll
            for (int Mt = 0; Mt < 4; Mt++)
#pragma unroll
                for (int Nt = 0; Nt < 4; Nt++)
                    acc[Mt][Nt] = __builtin_amdgcn_mfma_f32_16x16x32_bf16(
                        bv[Nt], av[Mt], acc[Mt][Nt], 0, 0, 0);
        }
    };

    // Bias fragments (uniform across tiles)
    float4 bsv[4];
#pragma unroll
    for (int Nt = 0; Nt < 4; Nt++)
        bsv[Nt] = *reinterpret_cast<const float4*>(bias + Nt*16 + q*4);

    // Epilogue for tile t. D layout: col(px-local)=m, row(co-local)=q*4+r.
    auto EPI = [&](int t) {
        int yout = Y0 + 4*t + w;
#pragma unroll
        for (int Mt = 0; Mt < 4; Mt++) {
            int px = X0 + Mt*16 + m;
#pragma unroll
            for (int Nt = 0; Nt < 4; Nt++) {
                int co0 = Nt*16 + q*4;
                float v0 = acc[Mt][Nt][0] + bsv[Nt].x;
                float v1 = acc[Mt][Nt][1] + bsv[Nt].y;
                float v2 = acc[Mt][Nt][2] + bsv[Nt].z;
                float v3 = acc[Mt][Nt][3] + bsv[Nt].w;
                if (MODE == 1) {
                    v0 = gelu_fast(v0); v1 = gelu_fast(v1);
                    v2 = gelu_fast(v2); v3 = gelu_fast(v3);
                    unsigned short* o = (unsigned short*)outp +
                        ((size_t)(n*NPAD + yout + 1)*NPAD + (px + 1))*64 + co0;
                    ushort4 pk = make_ushort4(f2bf(v0), f2bf(v1), f2bf(v2), f2bf(v3));
                    *reinterpret_cast<ushort4*>(o) = pk;
                } else {
                    float* o = (float*)outp +
                        ((size_t)(n*256 + yout)*256 + px)*64 + co0;
                    *reinterpret_cast<float4*>(o) = make_float4(v0, v1, v2, v3);
                }
            }
        }
    };

    // ---- 5-phase pipeline over (tile, half) with double-buffered LDS ----
    STAGE(0, 0, 0);
    __syncthreads();                       // prologue drain

    STAGE(0, 1, 1);                        // prefetch (t0,h1)
    ACCZERO();
    COMPUTE(0, 0);                         // compute (t0,h0)
    __syncthreads();

    STAGE(1, 0, 0);                        // prefetch (t1,h0)
    COMPUTE(1, 1);                         // compute (t0,h1) -> tile0 done
    __syncthreads();

    STAGE(1, 1, 1);                        // prefetch (t1,h1)
    EPI(0);                                // tile0 epilogue covers the stage
    ACCZERO();
    COMPUTE(0, 0);                         // compute (t1,h0)
    __syncthreads();

    COMPUTE(1, 1);                         // compute (t1,h1)
    EPI(1);
}

extern "C" void kernel_launch(void* const* d_in, const int* in_sizes, int n_in,
                              void* d_out, int out_size, void* d_ws, size_t ws_size,
                              hipStream_t stream)
{
    const float* means = (const float*)d_in[0];
    const float* feats = (const float*)d_in[2];
    const float* intr  = (const float*)d_in[3];
    const float* extr  = (const float*)d_in[4];
    const float* w1    = (const float*)d_in[5];
    const float* b1    = (const float*)d_in[6];
    const float* w2    = (const float*)d_in[7];
    const float* b2    = (const float*)d_in[8];

    char* ws = (char*)d_ws;
    int*            counts = (int*)(ws + O_COUNTS);
    float*          w2c    = (float*)(ws + O_W2C);
    unsigned short* wT     = (unsigned short*)(ws + O_WT);
    int*            meta   = (int*)(ws + O_META);
    unsigned short* fusedP = (unsigned short*)(ws + O_FUSED);
    unsigned short* x1P    = (unsigned short*)(ws + O_X1);

    prep_kernel<<<dim3(96), dim3(256), 0, stream>>>(
        extr, w1, w2, w2c, wT, fusedP, x1P, counts);
    proj_kernel<<<dim3(256, 12), dim3(256), 0, stream>>>(
        means, intr, w2c, meta, counts);
    fuse_kernel<<<dim3(4096, 8), dim3(256), 0, stream>>>(
        feats, meta, counts, fusedP);
    conv_kernel<1><<<dim3(4, 32, 8), dim3(256), 0, stream>>>(
        fusedP, wT, b1, (void*)x1P);
    conv_kernel<2><<<dim3(4, 32, 8), dim3(256), 0, stream>>>(
        x1P, wT + 36864, b2, d_out);
}